// Round 5
// baseline (103.066 us; speedup 1.0000x reference)
//
#include <hip/hip_runtime.h>

#define D_DIM 8192
#define SPLITK 16
#define KS (D_DIM / SPLITK)   // 512 per slice
#define NITER (KS / 32)       // 16 k-chunks of 32
#define NGROUP 320            // 32-weight-row groups (q:0-255, k:256-287, v:288-319)
#define GPB 4                 // groups per block = 1 per wave

typedef float f32x4 __attribute__((ext_vector_type(4)));
typedef short s16x8 __attribute__((ext_vector_type(8)));

__device__ __forceinline__ unsigned short f2bf(float f) {
  union { float f; unsigned u; } v; v.f = f;
  return (unsigned short)((v.u + 0x7FFFu + ((v.u >> 16) & 1u)) >> 16);
}

__device__ __forceinline__ s16x8 pack_bf16(f32x4 lo, f32x4 hi) {
  s16x8 r;
  r[0] = (short)f2bf(lo[0]); r[1] = (short)f2bf(lo[1]);
  r[2] = (short)f2bf(lo[2]); r[3] = (short)f2bf(lo[3]);
  r[4] = (short)f2bf(hi[0]); r[5] = (short)f2bf(hi[1]);
  r[6] = (short)f2bf(hi[2]); r[7] = (short)f2bf(hi[3]);
  return r;
}

// Named-register pipeline stage: 8 independent dwordx4 loads (issued together,
// no intervening consumer -> all 8 go into the vmcnt queue before any wait).
#define LOAD_STAGE(S, KO) do {                                                  \
    S##_a0l = *reinterpret_cast<const f32x4*>(ax0 + (KO));                      \
    S##_a0h = *reinterpret_cast<const f32x4*>(ax0 + (KO) + 4);                  \
    S##_a1l = *reinterpret_cast<const f32x4*>(ax1 + (KO));                      \
    S##_a1h = *reinterpret_cast<const f32x4*>(ax1 + (KO) + 4);                  \
    S##_b0l = *reinterpret_cast<const f32x4*>(bw0 + (KO));                      \
    S##_b0h = *reinterpret_cast<const f32x4*>(bw0 + (KO) + 4);                  \
    S##_b1l = *reinterpret_cast<const f32x4*>(bw1 + (KO));                      \
    S##_b1h = *reinterpret_cast<const f32x4*>(bw1 + (KO) + 4);                  \
  } while (0)

#define COMPUTE_STAGE(S) do {                                                   \
    s16x8 fa0 = pack_bf16(S##_a0l, S##_a0h);                                    \
    s16x8 fa1 = pack_bf16(S##_a1l, S##_a1h);                                    \
    s16x8 fb0 = pack_bf16(S##_b0l, S##_b0h);                                    \
    s16x8 fb1 = pack_bf16(S##_b1l, S##_b1h);                                    \
    acc00 = __builtin_amdgcn_mfma_f32_16x16x32_bf16(fa0, fb0, acc00, 0, 0, 0);  \
    acc10 = __builtin_amdgcn_mfma_f32_16x16x32_bf16(fa1, fb0, acc10, 0, 0, 0);  \
    acc01 = __builtin_amdgcn_mfma_f32_16x16x32_bf16(fa0, fb1, acc01, 0, 0, 0);  \
    acc11 = __builtin_amdgcn_mfma_f32_16x16x32_bf16(fa1, fb1, acc11, 0, 0, 0);  \
  } while (0)

// No LDS, no barriers: each wave computes a 32(batch)x32(weight-row) tile for
// one K-slice, loading MFMA fragments directly from global fp32 and converting
// to bf16 in registers. Explicit 2-deep software pipeline (stages A/B).
template <int MODE>  // 0 = workspace partials, 1 = atomicAdd fallback
__global__ __launch_bounds__(256, 4) void qkv_gemm(
    const float* __restrict__ x, const float* __restrict__ wq,
    const float* __restrict__ wk, const float* __restrict__ wv,
    float* __restrict__ wsb, float* __restrict__ out)
{
  const int bid   = blockIdx.x;
  const int ksl   = bid & (SPLITK - 1);
  const int gblk  = bid >> 4;                 // log2(SPLITK)
  const int w     = threadIdx.x >> 6;
  const int lane  = threadIdx.x & 63;
  const int group = gblk * GPB + w;           // 0..319
  const int n0    = group * 32;               // global weight row base

  const float* wptr; int erow0, outbase;
  if (n0 < 8192)      { wptr = wq; outbase = 0;      erow0 = n0; }
  else if (n0 < 9216) { wptr = wk; outbase = 262144; erow0 = n0 - 8192; }
  else                { wptr = wv; outbase = 294912; erow0 = n0 - 9216; }

  const int la = lane & 15;          // row within 16-tile
  const int kg = (lane >> 4) * 8;    // k-subgroup offset
  const size_t kbase = (size_t)ksl * KS;

  const float* ax0 = x    + (size_t)la * D_DIM + kbase + kg;            // batch 0-15
  const float* ax1 = ax0  + (size_t)16 * D_DIM;                         // batch 16-31
  const float* bw0 = wptr + (size_t)(erow0 + la) * D_DIM + kbase + kg;  // n-tile 0
  const float* bw1 = bw0  + (size_t)16 * D_DIM;                         // n-tile 1

  f32x4 acc00 = {0.f,0.f,0.f,0.f}, acc01 = {0.f,0.f,0.f,0.f};
  f32x4 acc10 = {0.f,0.f,0.f,0.f}, acc11 = {0.f,0.f,0.f,0.f};

  f32x4 A_a0l, A_a0h, A_a1l, A_a1h, A_b0l, A_b0h, A_b1l, A_b1h;
  f32x4 B_a0l, B_a0h, B_a1l, B_a1h, B_b0l, B_b0h, B_b1l, B_b1h;

  LOAD_STAGE(A, 0);
  LOAD_STAGE(B, 32);

  #pragma unroll
  for (int it = 0; it < NITER; it += 2) {
    COMPUTE_STAGE(A);                                    // B's loads in flight
    if (it + 2 < NITER) LOAD_STAGE(A, (it + 2) * 32);    // refill A early
    COMPUTE_STAGE(B);                                    // A's loads in flight
    if (it + 3 < NITER) LOAD_STAGE(B, (it + 3) * 32);    // refill B early
  }

  // C/D layout (verified R1-R4): col = lane&15 = n within tile, row = (lane>>4)*4+r = batch
  const int m0 = (lane >> 4) * 4;
  if (MODE == 0) {
    float* p = wsb + ((size_t)(ksl * NGROUP + group)) * 1024;  // [b][n] 32x32
    #pragma unroll
    for (int r = 0; r < 4; ++r) {
      p[(m0 + r) * 32 + la]           = acc00[r];
      p[(m0 + r) * 32 + 16 + la]      = acc01[r];
      p[(16 + m0 + r) * 32 + la]      = acc10[r];
      p[(16 + m0 + r) * 32 + 16 + la] = acc11[r];
    }
  } else {
    #pragma unroll
    for (int ni = 0; ni < 2; ++ni) {
      const int er    = erow0 + ni * 16 + la;
      const int obase = outbase + (er >> 7) * 4096 + (er & 127);
      f32x4 ac0 = ni ? acc01 : acc00;
      f32x4 ac1 = ni ? acc11 : acc10;
      #pragma unroll
      for (int r = 0; r < 4; ++r) {
        atomicAdd(&out[obase + (size_t)(m0 + r) * 128],      ac0[r]);
        atomicAdd(&out[obase + (size_t)(16 + m0 + r) * 128], ac1[r]);
      }
    }
  }
}

// Sum SPLITK partial tiles per group and scatter to head-layout output.
// Vectorized f32x4; summation order (sl ascending) identical to R4.
__global__ __launch_bounds__(256) void qkv_reduce(
    const float* __restrict__ ws, float* __restrict__ out)
{
  const int group = blockIdx.x;
  const int idx   = threadIdx.x * 4;          // b*32 + n, 4 consecutive n
  f32x4 s = {0.f, 0.f, 0.f, 0.f};
  #pragma unroll
  for (int sl = 0; sl < SPLITK; ++sl) {
    f32x4 v = *reinterpret_cast<const f32x4*>(
        ws + ((size_t)(sl * NGROUP + group)) * 1024 + idx);
    s[0] += v[0]; s[1] += v[1]; s[2] += v[2]; s[3] += v[3];
  }
  const int b = idx >> 5;
  const int n = idx & 31;
  const int e = group * 32 + n;
  int outbase, er;
  if (e < 8192)      { outbase = 0;      er = e; }
  else if (e < 9216) { outbase = 262144; er = e - 8192; }
  else               { outbase = 294912; er = e - 9216; }
  *reinterpret_cast<f32x4*>(out + outbase + (er >> 7) * 4096 + b * 128 + (er & 127)) = s;
}

extern "C" void kernel_launch(void* const* d_in, const int* in_sizes, int n_in,
                              void* d_out, int out_size, void* d_ws, size_t ws_size,
                              hipStream_t stream) {
  const float* x  = (const float*)d_in[0];
  const float* wq = (const float*)d_in[1];
  const float* wk = (const float*)d_in[2];
  const float* wv = (const float*)d_in[3];
  float* out = (float*)d_out;
  const size_t need = (size_t)SPLITK * NGROUP * 1024 * sizeof(float);
  if (ws_size >= need) {
    qkv_gemm<0><<<dim3(NGROUP / GPB * SPLITK), dim3(256), 0, stream>>>(
        x, wq, wk, wv, (float*)d_ws, out);
    qkv_reduce<<<dim3(NGROUP), dim3(256), 0, stream>>>((const float*)d_ws, out);
  } else {
    hipMemsetAsync(out, 0, (size_t)out_size * sizeof(float), stream);
    qkv_gemm<1><<<dim3(NGROUP / GPB * SPLITK), dim3(256), 0, stream>>>(
        x, wq, wk, wv, nullptr, out);
  }
}

// Round 6
// 94.194 us; speedup vs baseline: 1.0942x; 1.0942x over previous
//
#include <hip/hip_runtime.h>

#define D_DIM 8192
#define SPLITK 16
#define KS (D_DIM / SPLITK)   // 512 per slice
#define NITER (KS / 32)       // 16 k-chunks of 32
#define NGROUP 320            // 32-weight-row groups (q:0-255, k:256-287, v:288-319)
#define GPB 4                 // groups per block = 1 per wave

typedef float f32x4 __attribute__((ext_vector_type(4)));
typedef short s16x8 __attribute__((ext_vector_type(8)));

__device__ __forceinline__ unsigned short f2bf(float f) {
  union { float f; unsigned u; } v; v.f = f;
  return (unsigned short)((v.u + 0x7FFFu + ((v.u >> 16) & 1u)) >> 16);
}

__device__ __forceinline__ s16x8 pack_bf16(f32x4 lo, f32x4 hi) {
  s16x8 r;
  r[0] = (short)f2bf(lo[0]); r[1] = (short)f2bf(lo[1]);
  r[2] = (short)f2bf(lo[2]); r[3] = (short)f2bf(lo[3]);
  r[4] = (short)f2bf(hi[0]); r[5] = (short)f2bf(hi[1]);
  r[6] = (short)f2bf(hi[2]); r[7] = (short)f2bf(hi[3]);
  return r;
}

// No LDS, no barriers: each wave computes a 32(batch)x32(weight-row) tile for
// one K-slice, loading MFMA fragments directly from global fp32 and converting
// to bf16 in registers (R4 structure — compiler pipelines unroll-2 best).
// 1280 blocks = 5 blocks/CU exactly with min-waves 5 -> no straggler round.
template <int MODE>  // 0 = workspace partials, 1 = atomicAdd fallback
__global__ __launch_bounds__(256, 5) void qkv_gemm(
    const float* __restrict__ x, const float* __restrict__ wq,
    const float* __restrict__ wk, const float* __restrict__ wv,
    float* __restrict__ wsb, float* __restrict__ out)
{
  const int bid   = blockIdx.x;
  const int ksl   = bid & (SPLITK - 1);
  const int gblk  = bid >> 4;                 // log2(SPLITK)
  const int w     = threadIdx.x >> 6;
  const int lane  = threadIdx.x & 63;
  const int group = gblk * GPB + w;           // 0..319
  const int n0    = group * 32;               // global weight row base

  const float* wptr; int erow0, outbase;
  if (n0 < 8192)      { wptr = wq; outbase = 0;      erow0 = n0; }
  else if (n0 < 9216) { wptr = wk; outbase = 262144; erow0 = n0 - 8192; }
  else                { wptr = wv; outbase = 294912; erow0 = n0 - 9216; }

  const int la = lane & 15;          // row within 16-tile
  const int kg = (lane >> 4) * 8;    // k-subgroup offset
  const size_t kbase = (size_t)ksl * KS;

  const float* ax0 = x    + (size_t)la * D_DIM + kbase + kg;            // batch 0-15
  const float* ax1 = ax0  + (size_t)16 * D_DIM;                         // batch 16-31
  const float* bw0 = wptr + (size_t)(erow0 + la) * D_DIM + kbase + kg;  // n-tile 0
  const float* bw1 = bw0  + (size_t)16 * D_DIM;                         // n-tile 1

  f32x4 acc00 = {0.f,0.f,0.f,0.f}, acc01 = {0.f,0.f,0.f,0.f};
  f32x4 acc10 = {0.f,0.f,0.f,0.f}, acc11 = {0.f,0.f,0.f,0.f};

  #pragma unroll 2
  for (int it = 0; it < NITER; ++it) {
    const int ko = it * 32;
    f32x4 a0l = *reinterpret_cast<const f32x4*>(ax0 + ko);
    f32x4 a0h = *reinterpret_cast<const f32x4*>(ax0 + ko + 4);
    f32x4 a1l = *reinterpret_cast<const f32x4*>(ax1 + ko);
    f32x4 a1h = *reinterpret_cast<const f32x4*>(ax1 + ko + 4);
    f32x4 b0l = *reinterpret_cast<const f32x4*>(bw0 + ko);
    f32x4 b0h = *reinterpret_cast<const f32x4*>(bw0 + ko + 4);
    f32x4 b1l = *reinterpret_cast<const f32x4*>(bw1 + ko);
    f32x4 b1h = *reinterpret_cast<const f32x4*>(bw1 + ko + 4);

    s16x8 fa0 = pack_bf16(a0l, a0h);
    s16x8 fa1 = pack_bf16(a1l, a1h);
    s16x8 fb0 = pack_bf16(b0l, b0h);
    s16x8 fb1 = pack_bf16(b1l, b1h);

    acc00 = __builtin_amdgcn_mfma_f32_16x16x32_bf16(fa0, fb0, acc00, 0, 0, 0);
    acc10 = __builtin_amdgcn_mfma_f32_16x16x32_bf16(fa1, fb0, acc10, 0, 0, 0);
    acc01 = __builtin_amdgcn_mfma_f32_16x16x32_bf16(fa0, fb1, acc01, 0, 0, 0);
    acc11 = __builtin_amdgcn_mfma_f32_16x16x32_bf16(fa1, fb1, acc11, 0, 0, 0);
  }

  // C/D layout (verified R1-R5): col = lane&15 = n within tile, row = (lane>>4)*4+r = batch
  const int m0 = (lane >> 4) * 4;
  if (MODE == 0) {
    float* p = wsb + ((size_t)(ksl * NGROUP + group)) * 1024;  // [b][n] 32x32
    #pragma unroll
    for (int r = 0; r < 4; ++r) {
      p[(m0 + r) * 32 + la]           = acc00[r];
      p[(m0 + r) * 32 + 16 + la]      = acc01[r];
      p[(16 + m0 + r) * 32 + la]      = acc10[r];
      p[(16 + m0 + r) * 32 + 16 + la] = acc11[r];
    }
  } else {
    #pragma unroll
    for (int ni = 0; ni < 2; ++ni) {
      const int er    = erow0 + ni * 16 + la;
      const int obase = outbase + (er >> 7) * 4096 + (er & 127);
      f32x4 ac0 = ni ? acc01 : acc00;
      f32x4 ac1 = ni ? acc11 : acc10;
      #pragma unroll
      for (int r = 0; r < 4; ++r) {
        atomicAdd(&out[obase + (size_t)(m0 + r) * 128],      ac0[r]);
        atomicAdd(&out[obase + (size_t)(16 + m0 + r) * 128], ac1[r]);
      }
    }
  }
}

// Sum SPLITK partial tiles per group and scatter to head-layout output.
// Vectorized f32x4; summation order (sl ascending) identical to R4.
__global__ __launch_bounds__(256) void qkv_reduce(
    const float* __restrict__ ws, float* __restrict__ out)
{
  const int group = blockIdx.x;
  const int idx   = threadIdx.x * 4;          // b*32 + n, 4 consecutive n
  f32x4 s = {0.f, 0.f, 0.f, 0.f};
  #pragma unroll
  for (int sl = 0; sl < SPLITK; ++sl) {
    f32x4 v = *reinterpret_cast<const f32x4*>(
        ws + ((size_t)(sl * NGROUP + group)) * 1024 + idx);
    s[0] += v[0]; s[1] += v[1]; s[2] += v[2]; s[3] += v[3];
  }
  const int b = idx >> 5;
  const int n = idx & 31;
  const int e = group * 32 + n;
  int outbase, er;
  if (e < 8192)      { outbase = 0;      er = e; }
  else if (e < 9216) { outbase = 262144; er = e - 8192; }
  else               { outbase = 294912; er = e - 9216; }
  *reinterpret_cast<f32x4*>(out + outbase + (er >> 7) * 4096 + b * 128 + (er & 127)) = s;
}

extern "C" void kernel_launch(void* const* d_in, const int* in_sizes, int n_in,
                              void* d_out, int out_size, void* d_ws, size_t ws_size,
                              hipStream_t stream) {
  const float* x  = (const float*)d_in[0];
  const float* wq = (const float*)d_in[1];
  const float* wk = (const float*)d_in[2];
  const float* wv = (const float*)d_in[3];
  float* out = (float*)d_out;
  const size_t need = (size_t)SPLITK * NGROUP * 1024 * sizeof(float);
  if (ws_size >= need) {
    qkv_gemm<0><<<dim3(NGROUP / GPB * SPLITK), dim3(256), 0, stream>>>(
        x, wq, wk, wv, (float*)d_ws, out);
    qkv_reduce<<<dim3(NGROUP), dim3(256), 0, stream>>>((const float*)d_ws, out);
  } else {
    hipMemsetAsync(out, 0, (size_t)out_size * sizeof(float), stream);
    qkv_gemm<1><<<dim3(NGROUP / GPB * SPLITK), dim3(256), 0, stream>>>(
        x, wq, wk, wv, nullptr, out);
  }
}

// Round 7
// 89.844 us; speedup vs baseline: 1.1472x; 1.0484x over previous
//
#include <hip/hip_runtime.h>

#define D_DIM 8192
#define SPLITK 4
#define KS (D_DIM / SPLITK)   // 2048 per slice
#define BK 128
#define NITER (KS / BK)       // 16 chunks
#define NGROUP 320            // 32-weight-row groups (q:0-255, k:256-287, v:288-319)

typedef float f32x4 __attribute__((ext_vector_type(4)));
typedef short s16x8 __attribute__((ext_vector_type(8)));
typedef short s16x4 __attribute__((ext_vector_type(4)));

__device__ __forceinline__ unsigned short f2bf(float f) {
  union { float f; unsigned u; } v; v.f = f;
  return (unsigned short)((v.u + 0x7FFFu + ((v.u >> 16) & 1u)) >> 16);
}

// Load chunk CH: whole block cooperatively reads W tile (32 rows x 128 K) and
// X tile (32 batches x 128 K) as fp32. Each wave instruction covers two fully
// contiguous 512-B runs (32 lanes = one complete 128-float row slice) -- the
// DRAM-friendly pattern (vs 16 scattered 64-B half-lines in the reg-direct R4).
#define LOADG(CH) do {                                                          \
    const size_t kofs_ = kbase + (size_t)(CH) * BK;                             \
    _Pragma("unroll")                                                           \
    for (int i = 0; i < 4; ++i) {                                               \
      const int f_ = tid + i * 256;                                             \
      const int row_ = f_ >> 5, c4_ = f_ & 31;                                  \
      wr[i] = *reinterpret_cast<const f32x4*>(                                  \
          wptr + (size_t)(erow0 + row_) * D_DIM + kofs_ + c4_ * 4);             \
      xr[i] = *reinterpret_cast<const f32x4*>(                                  \
          x + (size_t)row_ * D_DIM + kofs_ + c4_ * 4);                          \
    } } while (0)

// Convert staged regs to bf16, write XOR-swizzled LDS buffer BUF.
// ushort offset: row*128 + (c4*4 ^ ((row&7)<<3))  [byte: row*256 + c4*8 ^ row<<4]
#define CVT_WRITE(BUF) do {                                                     \
    _Pragma("unroll")                                                           \
    for (int i = 0; i < 4; ++i) {                                               \
      const int f_ = tid + i * 256;                                             \
      const int row_ = f_ >> 5, c4_ = f_ & 31;                                  \
      const int off_ = row_ * BK + ((c4_ * 4) ^ ((row_ & 7) << 3));             \
      s16x4 wv_, xv_;                                                           \
      _Pragma("unroll")                                                         \
      for (int j = 0; j < 4; ++j) {                                             \
        wv_[j] = (short)f2bf(wr[i][j]);                                         \
        xv_[j] = (short)f2bf(xr[i][j]);                                         \
      }                                                                         \
      *reinterpret_cast<s16x4*>(&lds[BUF][0][off_]) = wv_;                      \
      *reinterpret_cast<s16x4*>(&lds[BUF][1][off_]) = xv_;                      \
    } } while (0)

// 4 K-steps of 32: each wave computes its 16x16 quadrant (wm = batch half,
// wn = weight-row half). A = X fragment, B = W fragment (swizzled reads).
#define COMPUTE(BUF) do {                                                       \
    _Pragma("unroll")                                                           \
    for (int s = 0; s < 4; ++s) {                                               \
      const int kc_ = s * 32 + kg;                                              \
      s16x8 af_ = *reinterpret_cast<const s16x8*>(                              \
          &lds[BUF][1][arow * BK + (kc_ ^ axor)]);                              \
      s16x8 bf_ = *reinterpret_cast<const s16x8*>(                              \
          &lds[BUF][0][brow * BK + (kc_ ^ bxor)]);                              \
      acc = __builtin_amdgcn_mfma_f32_16x16x32_bf16(af_, bf_, acc, 0, 0, 0);    \
    } } while (0)

template <int MODE>  // 0 = workspace partials, 1 = atomicAdd fallback
__global__ __launch_bounds__(256, 5) void qkv_gemm(
    const float* __restrict__ x, const float* __restrict__ wq,
    const float* __restrict__ wk, const float* __restrict__ wv,
    float* __restrict__ wsb, float* __restrict__ out)
{
  // [buf][0=W / 1=X][row * BK + col], bf16 as ushort. 2*2*32*128*2B = 32 KiB
  __shared__ unsigned short lds[2][2][32 * BK];

  const int bid   = blockIdx.x;
  const int ksl   = bid & (SPLITK - 1);
  const int group = bid >> 2;                 // log2(SPLITK)
  const int n0    = group * 32;

  const float* wptr; int erow0, outbase;
  if (n0 < 8192)      { wptr = wq; outbase = 0;      erow0 = n0; }
  else if (n0 < 9216) { wptr = wk; outbase = 262144; erow0 = n0 - 8192; }
  else                { wptr = wv; outbase = 294912; erow0 = n0 - 9216; }

  const int tid  = threadIdx.x;
  const int lane = tid & 63;
  const int w    = tid >> 6;
  const size_t kbase = (size_t)ksl * KS;

  // wave quadrant of the 32(batch) x 32(weight-row) tile
  const int wm   = w >> 1, wn = w & 1;
  const int la   = lane & 15;
  const int kg   = (lane >> 4) * 8;
  const int arow = wm * 16 + la;             // batch row in X tile
  const int brow = wn * 16 + la;             // weight row in W tile
  const int axor = (arow & 7) << 3;
  const int bxor = (brow & 7) << 3;

  f32x4 acc = {0.f, 0.f, 0.f, 0.f};
  f32x4 wr[4], xr[4];

  LOADG(0);
  CVT_WRITE(0);          // compiler waits vmcnt for wr/xr reads
  LOADG(1);              // chunk 1 in flight across the barrier
  __syncthreads();

  for (int c = 0; c < NITER; ++c) {
    COMPUTE(c & 1);
    if (c + 1 < NITER) {
      __syncthreads();                 // all waves done reading buf[(c+1)&1]
      CVT_WRITE((c + 1) & 1);          // vmcnt wait on chunk c+1 regs
      if (c + 2 < NITER) LOADG(c + 2); // next chunk in flight over compute
      __syncthreads();
    }
  }

  // C/D layout (verified R1-R6): col = lane&15 = n, row = (lane>>4)*4+r = batch
  const int m0 = (lane >> 4) * 4;
  if (MODE == 0) {
    float* p = wsb + ((size_t)(ksl * NGROUP + group)) * 1024;  // [b][n] 32x32
    #pragma unroll
    for (int r = 0; r < 4; ++r)
      p[(wm * 16 + m0 + r) * 32 + wn * 16 + la] = acc[r];
  } else {
    const int er    = erow0 + wn * 16 + la;
    const int obase = outbase + (er >> 7) * 4096 + (er & 127);
    #pragma unroll
    for (int r = 0; r < 4; ++r)
      atomicAdd(&out[obase + (size_t)(wm * 16 + m0 + r) * 128], acc[r]);
  }
}

// Sum SPLITK partial tiles per group and scatter to head-layout output.
__global__ __launch_bounds__(256) void qkv_reduce(
    const float* __restrict__ ws, float* __restrict__ out)
{
  const int group = blockIdx.x;
  const int idx   = threadIdx.x * 4;          // b*32 + n, 4 consecutive n
  f32x4 s = {0.f, 0.f, 0.f, 0.f};
  #pragma unroll
  for (int sl = 0; sl < SPLITK; ++sl) {
    f32x4 v = *reinterpret_cast<const f32x4*>(
        ws + ((size_t)(sl * NGROUP + group)) * 1024 + idx);
    s[0] += v[0]; s[1] += v[1]; s[2] += v[2]; s[3] += v[3];
  }
  const int b = idx >> 5;
  const int n = idx & 31;
  const int e = group * 32 + n;
  int outbase, er;
  if (e < 8192)      { outbase = 0;      er = e; }
  else if (e < 9216) { outbase = 262144; er = e - 8192; }
  else               { outbase = 294912; er = e - 9216; }
  *reinterpret_cast<f32x4*>(out + outbase + (er >> 7) * 4096 + b * 128 + (er & 127)) = s;
}

extern "C" void kernel_launch(void* const* d_in, const int* in_sizes, int n_in,
                              void* d_out, int out_size, void* d_ws, size_t ws_size,
                              hipStream_t stream) {
  const float* x  = (const float*)d_in[0];
  const float* wq = (const float*)d_in[1];
  const float* wk = (const float*)d_in[2];
  const float* wv = (const float*)d_in[3];
  float* out = (float*)d_out;
  const size_t need = (size_t)SPLITK * NGROUP * 1024 * sizeof(float);
  if (ws_size >= need) {
    qkv_gemm<0><<<dim3(NGROUP * SPLITK), dim3(256), 0, stream>>>(
        x, wq, wk, wv, (float*)d_ws, out);
    qkv_reduce<<<dim3(NGROUP), dim3(256), 0, stream>>>((const float*)d_ws, out);
  } else {
    hipMemsetAsync(out, 0, (size_t)out_size * sizeof(float), stream);
    qkv_gemm<1><<<dim3(NGROUP * SPLITK), dim3(256), 0, stream>>>(
        x, wq, wk, wv, nullptr, out);
  }
}